// Round 1
// baseline (553.455 us; speedup 1.0000x reference)
//
#include <hip/hip_runtime.h>
#include <hip/hip_bf16.h>
#include <math.h>

// Problem constants
// x:(4,128,96,96) gate_w:(8,128,3,3) gate_bias:(8) expert_w:(8,128,128,3,3)
// expert_b:(8,128) shared_w:(128,128,3,3) shared_b:(128)  -> out:(4,128,96,96)

typedef __attribute__((ext_vector_type(8))) short short8;
typedef __attribute__((ext_vector_type(4))) float f32x4;

static __device__ __forceinline__ unsigned short f2bf(float f) {
    unsigned int u = __float_as_uint(f);
    unsigned int r = (u + 0x7FFFu + ((u >> 16) & 1u)) >> 16;
    return (unsigned short)r;
}

// ---------------------------------------------------------------------------
// Prep: expert_w (8,128,128,3,3) + shared_w (128,128,3,3) -> bf16
// layout pw[e(9)][tap(9)][co(128)][ci(128)]
// ---------------------------------------------------------------------------
__global__ __launch_bounds__(256) void prep_kernel(
    const float* __restrict__ ew, const float* __restrict__ sw,
    unsigned short* __restrict__ pw)
{
    int i = blockIdx.x * 256 + threadIdx.x;
    if (i >= 9 * 9 * 128 * 128) return;
    int ci  = i & 127;
    int co  = (i >> 7) & 127;
    int et  = i >> 14;          // e*9 + tap
    int tap = et % 9;
    int e   = et / 9;
    float v = (e < 8) ? ew[((e * 128 + co) * 128 + ci) * 9 + tap]
                      : sw[(co * 128 + ci) * 9 + tap];
    pw[i] = f2bf(v);
}

// ---------------------------------------------------------------------------
// Gate: fp32 conv -> sigmoid -> top2 (biased) -> softmax(unbiased) ->
// dense score_full[b][e][h][w]  (zeros elsewhere)
// ---------------------------------------------------------------------------
__global__ __launch_bounds__(128) void gate_kernel(
    const float* __restrict__ x, const float* __restrict__ gw,
    const float* __restrict__ gb, float* __restrict__ scores)
{
    __shared__ float gws[9216];          // [ci][tap][e]
    int t = threadIdx.x;
    for (int i = t; i < 9216; i += 128) {
        int ci  = i / 72;
        int r   = i - ci * 72;
        int tap = r >> 3;
        int e   = r & 7;
        gws[i] = gw[(e * 128 + ci) * 9 + tap];
    }
    __syncthreads();

    int pix = blockIdx.x * 128 + t;      // grid is exactly 36864 threads
    int w   = pix % 96;
    int tmp = pix / 96;
    int h   = tmp % 96;
    int b   = tmp / 96;
    const float* xb = x + b * 128 * 9216;

    float acc[8] = {0.f,0.f,0.f,0.f,0.f,0.f,0.f,0.f};
    for (int ci = 0; ci < 128; ci++) {
        const float* xc = xb + ci * 9216;
        const float* wr = &gws[ci * 72];
        #pragma unroll
        for (int kh = 0; kh < 3; kh++) {
            int hh = h + kh - 1;
            if (hh < 0 || hh >= 96) continue;
            #pragma unroll
            for (int kw = 0; kw < 3; kw++) {
                int ww = w + kw - 1;
                if (ww < 0 || ww >= 96) continue;
                float xv = xc[hh * 96 + ww];
                const float* wp = wr + (kh * 3 + kw) * 8;
                #pragma unroll
                for (int e = 0; e < 8; e++) acc[e] += xv * wp[e];
            }
        }
    }

    float s[8], bs[8];
    #pragma unroll
    for (int e = 0; e < 8; e++) {
        s[e]  = 1.0f / (1.0f + expf(-acc[e]));
        bs[e] = s[e] + gb[e];
    }
    // top-1 (ties -> lowest index, matches lax.top_k)
    int i1 = 0; float b1 = bs[0]; float w1 = s[0];
    #pragma unroll
    for (int e = 1; e < 8; e++)
        if (bs[e] > b1) { b1 = bs[e]; i1 = e; w1 = s[e]; }
    // top-2
    int i2 = -1; float b2 = -1e30f; float w2 = 0.f;
    #pragma unroll
    for (int e = 0; e < 8; e++)
        if (e != i1 && bs[e] > b2) { b2 = bs[e]; i2 = e; w2 = s[e]; }

    float mx = fmaxf(w1, w2);
    float e1 = expf(w1 - mx), e2 = expf(w2 - mx);
    float inv = 1.0f / (e1 + e2);
    float p1 = e1 * inv, p2 = e2 * inv;   // ROUTE_SCALE = 1

    int base = b * 8 * 9216 + h * 96 + w;
    #pragma unroll
    for (int e = 0; e < 8; e++) {
        float v = (e == i1) ? p1 : ((e == i2) ? p2 : 0.0f);
        scores[base + e * 9216] = v;
    }
}

// ---------------------------------------------------------------------------
// Main: fused sparse MoE conv via implicit-GEMM MFMA (bf16 in, fp32 acc)
// Block tile: 128 Cout x 64 pixels (2 rows x 32 cols). 4 waves.
// ---------------------------------------------------------------------------
__global__ __launch_bounds__(256, 2) void moe_main_kernel(
    const float* __restrict__ x, const unsigned short* __restrict__ pw,
    const float* __restrict__ scores, const float* __restrict__ eb,
    const float* __restrict__ sb, float* __restrict__ out)
{
    __shared__ unsigned short xs[4 * 34 * 136]; // [row(4)][col(34)][ci 128 pad->136]
    __shared__ unsigned short wsl[128 * 136];   // [co][ci pad->136]
    __shared__ float sc[8][64];
    __shared__ float bia[9][128];
    __shared__ int   flags[8];

    const int t  = threadIdx.x;
    const int bx = blockIdx.x;
    const int wt = bx % 3;
    const int h2 = (bx / 3) % 48;
    const int b  = bx / 144;
    const int h0 = h2 * 2, w0 = wt * 32;

    // ---- stage x patch (4 rows x 34 cols x 128 ci), fp32 -> bf16, transposed
    const float* xb = x + b * 128 * 9216;
    for (int i = t; i < 17408; i += 256) {
        int ci  = i / 136;                // 136 = 4*34 (coincidence with pad)
        int rem = i - ci * 136;
        int row = rem / 34;
        int col = rem - row * 34;
        int hh = h0 - 1 + row;
        int ww = w0 - 1 + col;
        float v = 0.0f;
        if (hh >= 0 && hh < 96 && ww >= 0 && ww < 96)
            v = xb[ci * 9216 + hh * 96 + ww];
        xs[(row * 34 + col) * 136 + ci] = f2bf(v);
    }
    // ---- stage routing scores for the 64 pixels
    for (int i = t; i < 512; i += 256) {
        int e = i >> 6, p = i & 63;
        sc[e][p] = scores[(b * 8 + e) * 9216 + (h0 + (p >> 5)) * 96 + (w0 + (p & 31))];
    }
    // ---- stage biases (experts + shared as e=8)
    for (int i = t; i < 1152; i += 256) {
        int e = i >> 7, co = i & 127;
        bia[e][co] = (e < 8) ? eb[(e << 7) + co] : sb[co];
    }
    __syncthreads();
    if (t < 8) {
        int any = 0;
        for (int p = 0; p < 64; p++) any |= (sc[t][p] != 0.0f) ? 1 : 0;
        flags[t] = any;
    }
    __syncthreads();

    const int wv = t >> 6;
    const int l  = t & 63;
    const int lm = l & 15;   // m (A: co) / n (B: pixel) within frag
    const int lq = l >> 4;   // k-subgroup for A/B; row-group for D

    f32x4 acc[2][4];
    #pragma unroll
    for (int i2 = 0; i2 < 2; i2++)
        #pragma unroll
        for (int j = 0; j < 4; j++)
            acc[i2][j] = (f32x4){0.f, 0.f, 0.f, 0.f};

    const int aBase = (wv * 32 + lm) * 136 + lq * 8;
    const int bBase = lm * 136 + lq * 8;

    for (int e = 0; e < 9; e++) {
        if (e < 8 && !flags[e]) continue;   // block-uniform: exact-zero skip
        f32x4 accE[2][4];
        #pragma unroll
        for (int i2 = 0; i2 < 2; i2++)
            #pragma unroll
            for (int j = 0; j < 4; j++)
                accE[i2][j] = (f32x4){0.f, 0.f, 0.f, 0.f};

        const unsigned short* pwe = pw + e * 9 * 16384;
        for (int tap = 0; tap < 9; tap++) {
            __syncthreads();   // protect wsl from previous tap's readers
            const uint4* src = reinterpret_cast<const uint4*>(pwe + tap * 16384);
            #pragma unroll
            for (int it = 0; it < 8; it++) {
                int idx = t + (it << 8);        // uint4 index (2048 total)
                int co  = idx >> 4;
                int ci8 = (idx & 15) << 3;
                *reinterpret_cast<uint4*>(&wsl[co * 136 + ci8]) = src[idx];
            }
            __syncthreads();

            const int kh = tap / 3;
            const int kw = tap - kh * 3;
            const int xrow0 = kh * 4624 + kw * 136 + bBase;  // 4624 = 34*136
            #pragma unroll
            for (int kc = 0; kc < 4; kc++) {
                const short8 a0 = *reinterpret_cast<const short8*>(&wsl[aBase + kc * 32]);
                const short8 a1 = *reinterpret_cast<const short8*>(&wsl[aBase + 2176 + kc * 32]);
                #pragma unroll
                for (int j = 0; j < 4; j++) {
                    const short8 bv = *reinterpret_cast<const short8*>(
                        &xs[xrow0 + (j >> 1) * 4624 + (j & 1) * 2176 + kc * 32]);
                    accE[0][j] = __builtin_amdgcn_mfma_f32_16x16x32_bf16(a0, bv, accE[0][j], 0, 0, 0);
                    accE[1][j] = __builtin_amdgcn_mfma_f32_16x16x32_bf16(a1, bv, accE[1][j], 0, 0, 0);
                }
            }
        }
        // weighted accumulate: acc += s_e * (convE + b_e[co]); shared: s=1
        #pragma unroll
        for (int j = 0; j < 4; j++) {
            const int p = j * 16 + lm;
            const float s = (e < 8) ? sc[e][p] : 1.0f;
            #pragma unroll
            for (int i2 = 0; i2 < 2; i2++)
                #pragma unroll
                for (int rr = 0; rr < 4; rr++) {
                    const int co = wv * 32 + i2 * 16 + lq * 4 + rr;
                    acc[i2][j][rr] += s * (accE[i2][j][rr] + bia[e][co]);
                }
        }
    }

    // ---- store (D frag: col = lm -> pixel, row = lq*4+rr -> co)
    float* ob = out + b * 128 * 9216;
    #pragma unroll
    for (int i2 = 0; i2 < 2; i2++)
        #pragma unroll
        for (int rr = 0; rr < 4; rr++) {
            const int co = wv * 32 + i2 * 16 + lq * 4 + rr;
            #pragma unroll
            for (int j = 0; j < 4; j++) {
                const int hh = h0 + (j >> 1);
                const int ww = w0 + (j & 1) * 16 + lm;
                ob[co * 9216 + hh * 96 + ww] = acc[i2][j][rr];
            }
        }
}

// ---------------------------------------------------------------------------
extern "C" void kernel_launch(void* const* d_in, const int* in_sizes, int n_in,
                              void* d_out, int out_size, void* d_ws, size_t ws_size,
                              hipStream_t stream) {
    const float* x  = (const float*)d_in[0];
    const float* gw = (const float*)d_in[1];
    const float* gb = (const float*)d_in[2];
    const float* ew = (const float*)d_in[3];
    const float* eb = (const float*)d_in[4];
    const float* sw = (const float*)d_in[5];
    const float* sb = (const float*)d_in[6];
    float* out = (float*)d_out;

    unsigned short* pw = (unsigned short*)d_ws;                  // 2,654,208 B
    float* scores = (float*)((char*)d_ws + 2654208);             // 1,179,648 B

    prep_kernel<<<5184, 256, 0, stream>>>(ew, sw, pw);
    gate_kernel<<<288, 128, 0, stream>>>(x, gw, gb, scores);
    moe_main_kernel<<<576, 256, 0, stream>>>(x, pw, scores, eb, sb, out);
}

// Round 2
// 350.528 us; speedup vs baseline: 1.5789x; 1.5789x over previous
//
#include <hip/hip_runtime.h>
#include <hip/hip_bf16.h>
#include <math.h>

// Problem constants
// x:(4,128,96,96) gate_w:(8,128,3,3) gate_bias:(8) expert_w:(8,128,128,3,3)
// expert_b:(8,128) shared_w:(128,128,3,3) shared_b:(128)  -> out:(4,128,96,96)

typedef __attribute__((ext_vector_type(8))) short short8;
typedef __attribute__((ext_vector_type(4))) float f32x4;

static __device__ __forceinline__ unsigned short f2bf(float f) {
    unsigned int u = __float_as_uint(f);
    unsigned int r = (u + 0x7FFFu + ((u >> 16) & 1u)) >> 16;
    return (unsigned short)r;
}

// ---------------------------------------------------------------------------
// Prep: expert_w (8,128,128,3,3) + shared_w (128,128,3,3) -> bf16
// layout pw[e(9)][tap(9)][co(128)][ci(128)]
// ---------------------------------------------------------------------------
__global__ __launch_bounds__(256) void prep_kernel(
    const float* __restrict__ ew, const float* __restrict__ sw,
    unsigned short* __restrict__ pw)
{
    int i = blockIdx.x * 256 + threadIdx.x;
    if (i >= 9 * 9 * 128 * 128) return;
    int ci  = i & 127;
    int co  = (i >> 7) & 127;
    int et  = i >> 14;          // e*9 + tap
    int tap = et % 9;
    int e   = et / 9;
    float v = (e < 8) ? ew[((e * 128 + co) * 128 + ci) * 9 + tap]
                      : sw[(co * 128 + ci) * 9 + tap];
    pw[i] = f2bf(v);
}

// ---------------------------------------------------------------------------
// Gate v2: fp32 conv -> sigmoid -> top2 -> softmax -> dense score_full.
// Block = 256 threads: 4 ci-groups x 64 pixels (2 rows x 32 cols).
// Grid = 576 blocks (b x h2 x wt) => 2304 waves (~9 waves/CU).
// ---------------------------------------------------------------------------
__global__ __launch_bounds__(256) void gate_kernel(
    const float* __restrict__ x, const float* __restrict__ gw,
    const float* __restrict__ gb, float* __restrict__ scores)
{
    __shared__ float gws[9216];          // [ci][tap][e] — wave-uniform reads
    __shared__ float red[4][64][8];      // partial sums per ci-group

    const int t = threadIdx.x;
    for (int i = t; i < 9216; i += 256) {
        int ci  = i / 72;
        int r   = i - ci * 72;
        int tap = r >> 3;
        int e   = r & 7;
        gws[i] = gw[(e * 128 + ci) * 9 + tap];
    }
    __syncthreads();

    const int g  = t >> 6;               // ci group (wave id)
    const int p  = t & 63;
    const int bx = blockIdx.x;
    const int wt = bx % 3;
    const int h2 = (bx / 3) % 48;
    const int b  = bx / 144;
    const int h  = h2 * 2 + (p >> 5);
    const int w  = wt * 32 + (p & 31);

    // Hoist border handling: 9 clamped offsets + 0/1 masks (per thread).
    int off[9]; float msk[9];
    #pragma unroll
    for (int kh = 0; kh < 3; kh++) {
        #pragma unroll
        for (int kw = 0; kw < 3; kw++) {
            int hh = h + kh - 1, ww = w + kw - 1;
            bool valid = (hh >= 0 && hh < 96 && ww >= 0 && ww < 96);
            int hc = min(max(hh, 0), 95), wc = min(max(ww, 0), 95);
            off[kh * 3 + kw] = hc * 96 + wc;
            msk[kh * 3 + kw] = valid ? 1.0f : 0.0f;
        }
    }

    const float* xb = x + (b * 128 + g * 32) * 9216;
    float acc[8] = {0.f,0.f,0.f,0.f,0.f,0.f,0.f,0.f};
    #pragma unroll 2
    for (int ci = 0; ci < 32; ci++) {
        const float* xc = xb + ci * 9216;
        const float* wr = &gws[(g * 32 + ci) * 72];
        float xv[9];
        #pragma unroll
        for (int tap = 0; tap < 9; tap++) xv[tap] = xc[off[tap]] * msk[tap];
        #pragma unroll
        for (int tap = 0; tap < 9; tap++) {
            #pragma unroll
            for (int e = 0; e < 8; e++) acc[e] += xv[tap] * wr[tap * 8 + e];
        }
    }

    #pragma unroll
    for (int e = 0; e < 8; e++) red[g][p][e] = acc[e];
    __syncthreads();

    if (t < 64) {
        float s[8], bs[8];
        #pragma unroll
        for (int e = 0; e < 8; e++) {
            float v = red[0][t][e] + red[1][t][e] + red[2][t][e] + red[3][t][e];
            s[e]  = 1.0f / (1.0f + expf(-v));
            bs[e] = s[e] + gb[e];
        }
        // top-1 (ties -> lowest index, matches lax.top_k)
        int i1 = 0; float b1 = bs[0]; float w1 = s[0];
        #pragma unroll
        for (int e = 1; e < 8; e++)
            if (bs[e] > b1) { b1 = bs[e]; i1 = e; w1 = s[e]; }
        int i2 = -1; float b2 = -1e30f; float w2 = 0.f;
        #pragma unroll
        for (int e = 0; e < 8; e++)
            if (e != i1 && bs[e] > b2) { b2 = bs[e]; i2 = e; w2 = s[e]; }

        float mx = fmaxf(w1, w2);
        float e1 = expf(w1 - mx), e2 = expf(w2 - mx);
        float inv = 1.0f / (e1 + e2);
        float p1 = e1 * inv, p2 = e2 * inv;   // ROUTE_SCALE = 1

        const int hh = h2 * 2 + (t >> 5);
        const int ww = wt * 32 + (t & 31);
        int base = b * 8 * 9216 + hh * 96 + ww;
        #pragma unroll
        for (int e = 0; e < 8; e++) {
            float v = (e == i1) ? p1 : ((e == i2) ? p2 : 0.0f);
            scores[base + e * 9216] = v;
        }
    }
}

// ---------------------------------------------------------------------------
// Main: fused dense MoE conv via implicit-GEMM MFMA (bf16 in, fp32 acc)
// Block tile: 128 Cout x 64 pixels (2 rows x 32 cols). 4 waves.
// ---------------------------------------------------------------------------
__global__ __launch_bounds__(256, 2) void moe_main_kernel(
    const float* __restrict__ x, const unsigned short* __restrict__ pw,
    const float* __restrict__ scores, const float* __restrict__ eb,
    const float* __restrict__ sb, float* __restrict__ out)
{
    __shared__ unsigned short xs[4 * 34 * 136]; // [row(4)][col(34)][ci 128 pad->136]
    __shared__ unsigned short wsl[128 * 136];   // [co][ci pad->136]
    __shared__ float sc[8][64];
    __shared__ float bia[9][128];

    const int t  = threadIdx.x;
    const int bx = blockIdx.x;
    const int wt = bx % 3;
    const int h2 = (bx / 3) % 48;
    const int b  = bx / 144;
    const int h0 = h2 * 2, w0 = wt * 32;

    // ---- stage x patch (4 rows x 34 cols x 128 ci), fp32 -> bf16, transposed
    const float* xb = x + b * 128 * 9216;
    for (int i = t; i < 17408; i += 256) {
        int ci  = i / 136;
        int rem = i - ci * 136;
        int row = rem / 34;
        int col = rem - row * 34;
        int hh = h0 - 1 + row;
        int ww = w0 - 1 + col;
        float v = 0.0f;
        if (hh >= 0 && hh < 96 && ww >= 0 && ww < 96)
            v = xb[ci * 9216 + hh * 96 + ww];
        xs[(row * 34 + col) * 136 + ci] = f2bf(v);
    }
    // ---- stage routing scores for the 64 pixels
    for (int i = t; i < 512; i += 256) {
        int e = i >> 6, p = i & 63;
        sc[e][p] = scores[(b * 8 + e) * 9216 + (h0 + (p >> 5)) * 96 + (w0 + (p & 31))];
    }
    // ---- stage biases (experts + shared as e=8)
    for (int i = t; i < 1152; i += 256) {
        int e = i >> 7, co = i & 127;
        bia[e][co] = (e < 8) ? eb[(e << 7) + co] : sb[co];
    }
    __syncthreads();

    const int wv = t >> 6;
    const int l  = t & 63;
    const int lm = l & 15;   // m (A: co) / n (B: pixel) within frag
    const int lq = l >> 4;   // k-subgroup for A/B; row-group for D

    f32x4 acc[2][4];
    #pragma unroll
    for (int i2 = 0; i2 < 2; i2++)
        #pragma unroll
        for (int j = 0; j < 4; j++)
            acc[i2][j] = (f32x4){0.f, 0.f, 0.f, 0.f};

    const int aBase = (wv * 32 + lm) * 136 + lq * 8;
    const int bBase = lm * 136 + lq * 8;

    for (int e = 0; e < 9; e++) {
        f32x4 accE[2][4];
        #pragma unroll
        for (int i2 = 0; i2 < 2; i2++)
            #pragma unroll
            for (int j = 0; j < 4; j++)
                accE[i2][j] = (f32x4){0.f, 0.f, 0.f, 0.f};

        const unsigned short* pwe = pw + e * 9 * 16384;
        for (int tap = 0; tap < 9; tap++) {
            __syncthreads();   // protect wsl from previous tap's readers
            const uint4* src = reinterpret_cast<const uint4*>(pwe + tap * 16384);
            #pragma unroll
            for (int it = 0; it < 8; it++) {
                int idx = t + (it << 8);        // uint4 index (2048 total)
                int co  = idx >> 4;
                int ci8 = (idx & 15) << 3;
                *reinterpret_cast<uint4*>(&wsl[co * 136 + ci8]) = src[idx];
            }
            __syncthreads();

            const int kh = tap / 3;
            const int kw = tap - kh * 3;
            const int xrow0 = kh * 4624 + kw * 136 + bBase;  // 4624 = 34*136
            #pragma unroll
            for (int kc = 0; kc < 4; kc++) {
                const short8 a0 = *reinterpret_cast<const short8*>(&wsl[aBase + kc * 32]);
                const short8 a1 = *reinterpret_cast<const short8*>(&wsl[aBase + 2176 + kc * 32]);
                #pragma unroll
                for (int j = 0; j < 4; j++) {
                    const short8 bv = *reinterpret_cast<const short8*>(
                        &xs[xrow0 + (j >> 1) * 4624 + (j & 1) * 2176 + kc * 32]);
                    accE[0][j] = __builtin_amdgcn_mfma_f32_16x16x32_bf16(a0, bv, accE[0][j], 0, 0, 0);
                    accE[1][j] = __builtin_amdgcn_mfma_f32_16x16x32_bf16(a1, bv, accE[1][j], 0, 0, 0);
                }
            }
        }
        // weighted accumulate: acc += s_e * (convE + b_e[co]); shared: s=1
        #pragma unroll
        for (int j = 0; j < 4; j++) {
            const int p = j * 16 + lm;
            const float s = (e < 8) ? sc[e][p] : 1.0f;
            #pragma unroll
            for (int i2 = 0; i2 < 2; i2++)
                #pragma unroll
                for (int rr = 0; rr < 4; rr++) {
                    const int co = wv * 32 + i2 * 16 + lq * 4 + rr;
                    acc[i2][j][rr] += s * (accE[i2][j][rr] + bia[e][co]);
                }
        }
    }

    // ---- store (D frag: col = lm -> pixel, row = lq*4+rr -> co)
    float* ob = out + b * 128 * 9216;
    #pragma unroll
    for (int i2 = 0; i2 < 2; i2++)
        #pragma unroll
        for (int rr = 0; rr < 4; rr++) {
            const int co = wv * 32 + i2 * 16 + lq * 4 + rr;
            #pragma unroll
            for (int j = 0; j < 4; j++) {
                const int hh = h0 + (j >> 1);
                const int ww = w0 + (j & 1) * 16 + lm;
                ob[co * 9216 + hh * 96 + ww] = acc[i2][j][rr];
            }
        }
}

// ---------------------------------------------------------------------------
extern "C" void kernel_launch(void* const* d_in, const int* in_sizes, int n_in,
                              void* d_out, int out_size, void* d_ws, size_t ws_size,
                              hipStream_t stream) {
    const float* x  = (const float*)d_in[0];
    const float* gw = (const float*)d_in[1];
    const float* gb = (const float*)d_in[2];
    const float* ew = (const float*)d_in[3];
    const float* eb = (const float*)d_in[4];
    const float* sw = (const float*)d_in[5];
    const float* sb = (const float*)d_in[6];
    float* out = (float*)d_out;

    unsigned short* pw = (unsigned short*)d_ws;                  // 2,654,208 B
    float* scores = (float*)((char*)d_ws + 2654208);             // 1,179,648 B

    prep_kernel<<<5184, 256, 0, stream>>>(ew, sw, pw);
    gate_kernel<<<576, 256, 0, stream>>>(x, gw, gb, scores);
    moe_main_kernel<<<576, 256, 0, stream>>>(x, pw, scores, eb, sb, out);
}